// Round 16
// baseline (394.604 us; speedup 1.0000x reference)
//
#include <hip/hip_runtime.h>

typedef __bf16 bf16_t;
typedef __bf16 bf16x8 __attribute__((ext_vector_type(8)));
typedef __bf16 bf16x4 __attribute__((ext_vector_type(4)));
typedef float  f32x4  __attribute__((ext_vector_type(4)));

#define HW_ 65536
#define C_  128

// XOR swizzle: spread 16B slots (byte bits [6:4]) by row index. Applied
// identically on LDS write and read; bijective within each 128B span.
__device__ __forceinline__ int swz(int r) { return ((r ^ (r >> 3)) & 7) << 4; }

#define LGKM0()  asm volatile("s_waitcnt lgkmcnt(0)" ::: "memory")
#define VMCNT0() asm volatile("s_waitcnt vmcnt(0)" ::: "memory")
__device__ __forceinline__ void BAR() {
  asm volatile("" ::: "memory");
  __builtin_amdgcn_s_barrier();
  asm volatile("" ::: "memory");
}

typedef __attribute__((address_space(1))) const unsigned int g_u32;
typedef __attribute__((address_space(3))) unsigned int l_u32;

// =====================================================================
// Prep: W f32 -> bf16, written as the EXACT 32KB swizzled LDS image each
// conv tile wants: img_byte[(o*256 + c*2) ^ swz(o)] = bf16(W[o][c]).
// =====================================================================
__global__ void wprep_kernel(const float* __restrict__ Wf, const float* __restrict__ Wg,
                             const float* __restrict__ Wh, bf16_t* __restrict__ dst)
{
  int i = blockIdx.x * 256 + threadIdx.x;          // 0..16383
  int o = i >> 7, c = i & 127;
  int boff = (o * 256 + c * 2) ^ swz(o);
  char* d = (char*)dst;
  *(bf16_t*)(d + boff)         = (bf16_t)Wf[i];
  *(bf16_t*)(d + 32768 + boff) = (bf16_t)Wg[i];
  *(bf16_t*)(d + 65536 + boff) = (bf16_t)Wh[i];
}

// =====================================================================
// Phase 1 (R15 form; async W staging): map = PReLU(W*x + b).
// HBLK: mH W32-blocked [c][w>>5][h][w&31] for attn's direct PV A-reads.
// =====================================================================
__device__ __forceinline__ void stage_w(char* lds, const bf16_t* __restrict__ Wimg,
                                        int wv, int t)
{
  #pragma unroll
  for (int rep = 0; rep < 8; ++rep) {
    const char* src = (const char*)Wimg + (rep * 256 + t) * 16;
    char* dst = lds + 32768 + (rep * 4 + wv) * 1024;      // wave-uniform base
    __builtin_amdgcn_global_load_lds((g_u32*)src, (l_u32*)dst, 16, 0, 0);
  }
}

__device__ __forceinline__ void conv_mfma(const char* lds, f32x4 (&acc)[2][8],
                                          int wv, int lr, int lq)
{
  const f32x4 fz = {0.f, 0.f, 0.f, 0.f};
  #pragma unroll
  for (int mf = 0; mf < 2; ++mf)
    #pragma unroll
    for (int nf = 0; nf < 8; ++nf)
      acc[mf][nf] = fz;

  #pragma unroll
  for (int ks = 0; ks < 4; ++ks) {
    int kb = ks * 32 + lq * 8;
    bf16x8 a[2], bb[8];
    #pragma unroll
    for (int mf = 0; mf < 2; ++mf) {
      int m = wv * 32 + mf * 16 + lr;
      a[mf] = *(const bf16x8*)(lds + 32768 + ((m * 256 + kb * 2) ^ swz(m)));
    }
    #pragma unroll
    for (int nf = 0; nf < 8; ++nf) {
      int n = nf * 16 + lr;
      bb[nf] = *(const bf16x8*)(lds + ((n * 256 + kb * 2) ^ swz(n)));
    }
    #pragma unroll
    for (int mf = 0; mf < 2; ++mf)
      #pragma unroll
      for (int nf = 0; nf < 8; ++nf)
        acc[mf][nf] = __builtin_amdgcn_mfma_f32_16x16x32_bf16(a[mf], bb[nf], acc[mf][nf], 0, 0, 0);
  }
}

template<bool HBLK>
__device__ __forceinline__ void conv_epi(const f32x4 (&acc)[2][8],
                                         const float* __restrict__ bias, float alpha,
                                         bf16_t* __restrict__ dst, size_t pb,
                                         int wv, int lr, int lq, int s0)
{
  #pragma unroll
  for (int mf = 0; mf < 2; ++mf) {
    #pragma unroll
    for (int i = 0; i < 4; ++i) {
      int o = wv * 32 + mf * 16 + lq * 4 + i;
      float bo = bias[o];
      #pragma unroll
      for (int nf = 0; nf < 8; ++nf) {
        int s = s0 + nf * 16 + lr;
        float v = acc[mf][nf][i] + bo;
        v = (v >= 0.f) ? v : alpha * v;
        size_t off;
        if (HBLK) {                       // W32-blocked [c][w>>5][h][w&31]
          int h = s >> 8, w = s & 255;
          off = pb + (size_t)o * HW_ + (size_t)(w >> 5) * 8192 + h * 32 + (w & 31);
        } else {
          off = pb + (size_t)o * HW_ + s; // natural [c][h][w]
        }
        dst[off] = (bf16_t)v;
      }
    }
  }
}

__global__ __launch_bounds__(256, 2) void conv_kernel(
    const float* __restrict__ x, const bf16_t* __restrict__ Wimg,
    const float* __restrict__ bfp, const float* __restrict__ afp,
    const float* __restrict__ bgp, const float* __restrict__ agp,
    const float* __restrict__ bhp, const float* __restrict__ ahp,
    bf16_t* __restrict__ mF, bf16_t* __restrict__ mG, bf16_t* __restrict__ mH, int b0)
{
  __shared__ __align__(16) char lds[65536];
  const int t = threadIdx.x;
  const int bloc = blockIdx.y;
  const int s0 = blockIdx.x * 128;
  const size_t xbase = ((size_t)(b0 + bloc) * C_) * HW_ + s0;
  const int wv = t >> 6, lane = t & 63, lr = lane & 15, lq = lane >> 4;
  const size_t pb = (size_t)bloc * C_ * HW_;

  // issue W_f staging async; stage x tile meanwhile
  stage_w(lds, Wimg, wv, t);

  #pragma unroll
  for (int rep = 0; rep < 4; ++rep) {
    int q = rep * 256 + t;
    int c0 = (q >> 5) * 4, sl0 = (q & 31) * 4;
    f32x4 r[4];
    #pragma unroll
    for (int i = 0; i < 4; ++i)
      r[i] = *(const f32x4*)(x + xbase + (size_t)(c0 + i) * HW_ + sl0);
    #pragma unroll
    for (int js = 0; js < 4; ++js) {
      int s = sl0 + js;
      bf16x4 v;
      v[0] = (bf16_t)r[0][js]; v[1] = (bf16_t)r[1][js];
      v[2] = (bf16_t)r[2][js]; v[3] = (bf16_t)r[3][js];
      *(bf16x4*)(lds + ((s * 256 + c0 * 2) ^ swz(s))) = v;
    }
  }
  __syncthreads();                       // Xs lgkm + W_f vmcnt drained

  f32x4 acc[2][8];

  // ---- conv f ----
  conv_mfma(lds, acc, wv, lr, lq);
  BAR();                                 // all Ws(f) reads done
  stage_w(lds, Wimg + 16384, wv, t);     // W_g streams under f's epilogue
  conv_epi<false>(acc, bfp, afp[0], mF, pb, wv, lr, lq, s0);
  VMCNT0(); BAR();                       // W_g landed everywhere

  // ---- conv g ----
  conv_mfma(lds, acc, wv, lr, lq);
  BAR();
  stage_w(lds, Wimg + 32768, wv, t);     // W_h streams under g's epilogue
  conv_epi<false>(acc, bgp, agp[0], mG, pb, wv, lr, lq, s0);
  VMCNT0(); BAR();

  // ---- conv h ----
  conv_mfma(lds, acc, wv, lr, lq);
  conv_epi<true>(acc, bhp, ahp[0], mH, pb, wv, lr, lq, s0);
}

// =====================================================================
// Phase 2 (R15 S/softmax + R7 zero-barrier PV): 512 thr / 8 waves.
// LDS map (135168 B):
//   [0,32768)        Ft chunk  [w=256][h=64] bf16 swizzled   (S phase)
//   [32768,65536)    Gt chunk  [v=256][h=64] bf16 swizzled   (S phase)
//   [0,131072)       PT        [v=256][w=256] bf16 swizzled  (PV phase)
//   [131072,133120)  smax [2][256] f32 ; [133120,135168) ssum [2][256] f32
// S: depth-1 global prefetch kept in flight across raw barriers (T14).
// PV: A = H direct from global (W32-blocked mH; wave owns 32 unique
//     h-rows; 1KB contiguous fragment reads; 3-deep reg pipeline aP[3][2]
//     REPLACES the Hs bounce+hreg) -> ZERO barriers in the PV loop.
// Register file is FULL at 2 waves/SIMD — no additive state (R11-R13).
// =====================================================================
#define GT_OFF  32768
#define SMAX_OFF 131072
#define SSUM_OFF 133120
#define SMEM_BYTES 135168

__global__ __launch_bounds__(512, 2) void attn_kernel(
    const bf16_t* __restrict__ mF, const bf16_t* __restrict__ mG, const bf16_t* __restrict__ mH,
    const float* __restrict__ x, float* __restrict__ out, int b0)
{
  extern __shared__ __align__(16) char smem[];
  const int t = threadIdx.x;
  const int c = blockIdx.x, bloc = blockIdx.y;
  const int wv = t >> 6, lane = t & 63, lr = lane & 15, lq = lane >> 4;
  const int wr = wv >> 1, wc = wv & 1;
  const size_t plane  = ((size_t)bloc * C_ + c) * HW_;            // maps (per-pass)
  const size_t gplane = (((size_t)(b0 + bloc)) * C_ + c) * HW_;   // x / out (global)

  const f32x4 fz = {0.f, 0.f, 0.f, 0.f};
  f32x4 acc[4][8];
  #pragma unroll
  for (int mf = 0; mf < 4; ++mf)
    #pragma unroll
    for (int nf = 0; nf < 8; ++nf)
      acc[mf][nf] = fz;

  const int hq = t >> 5, wb8 = t & 31;   // staging decomposition

  // ---- S = F^T G, K(=h) chunks of 64; depth-1 prefetch across barriers ----
  bf16x8 pfF[4], pfG[4];
  #pragma unroll
  for (int i = 0; i < 4; ++i) {
    pfF[i] = *(const bf16x8*)(mF + plane + (size_t)(hq * 4 + i) * 256 + wb8 * 8);
    pfG[i] = *(const bf16x8*)(mG + plane + (size_t)(hq * 4 + i) * 256 + wb8 * 8);
  }

  for (int hb = 0; hb < 256; hb += 64) {
    BAR();                             // prev chunk's LDS reads done; Ft/Gt writable
    #pragma unroll
    for (int j = 0; j < 8; ++j) {      // transpose-write (waits vmcnt on pf regs)
      int w = wb8 * 8 + j;
      bf16x4 v; v[0] = pfF[0][j]; v[1] = pfF[1][j]; v[2] = pfF[2][j]; v[3] = pfF[3][j];
      *(bf16x4*)(smem + ((w * 128 + hq * 8) ^ swz(w))) = v;
      bf16x4 g; g[0] = pfG[0][j]; g[1] = pfG[1][j]; g[2] = pfG[2][j]; g[3] = pfG[3][j];
      *(bf16x4*)(smem + GT_OFF + ((w * 128 + hq * 8) ^ swz(w))) = g;
    }
    if (hb < 192) {                    // issue next chunk; flies across BAR + MFMAs
      #pragma unroll
      for (int i = 0; i < 4; ++i) {
        pfF[i] = *(const bf16x8*)(mF + plane + (size_t)(hb + 64 + hq * 4 + i) * 256 + wb8 * 8);
        pfG[i] = *(const bf16x8*)(mG + plane + (size_t)(hb + 64 + hq * 4 + i) * 256 + wb8 * 8);
      }
    }
    LGKM0(); BAR();                    // LDS writes visible; vmcnt NOT drained
    #pragma unroll
    for (int k0 = 0; k0 < 64; k0 += 32) {
      int kb = k0 + lq * 8;
      bf16x8 a[4], bb[8];
      #pragma unroll
      for (int mf = 0; mf < 4; ++mf) {
        int m = wr * 64 + mf * 16 + lr;
        a[mf] = *(const bf16x8*)(smem + ((m * 128 + kb * 2) ^ swz(m)));
      }
      #pragma unroll
      for (int nf = 0; nf < 8; ++nf) {
        int n = wc * 128 + nf * 16 + lr;
        bb[nf] = *(const bf16x8*)(smem + GT_OFF + ((n * 128 + kb * 2) ^ swz(n)));
      }
      #pragma unroll
      for (int mf = 0; mf < 4; ++mf)
        #pragma unroll
        for (int nf = 0; nf < 8; ++nf)
          acc[mf][nf] = __builtin_amdgcn_mfma_f32_16x16x32_bf16(a[mf], bb[nf], acc[mf][nf], 0, 0, 0);
    }
  }

  // ---- softmax over v (rows w) ----
  float* smax = (float*)(smem + SMAX_OFF);
  float* ssum = (float*)(smem + SSUM_OFF);
  float rowm[4][4];
  #pragma unroll
  for (int mf = 0; mf < 4; ++mf)
    #pragma unroll
    for (int i = 0; i < 4; ++i) {
      float m = acc[mf][0][i];
      #pragma unroll
      for (int nf = 1; nf < 8; ++nf) m = fmaxf(m, acc[mf][nf][i]);
      #pragma unroll
      for (int d = 1; d < 16; d <<= 1) m = fmaxf(m, __shfl_xor(m, d));
      rowm[mf][i] = m;
    }
  if (lr == 0) {
    #pragma unroll
    for (int mf = 0; mf < 4; ++mf)
      #pragma unroll
      for (int i = 0; i < 4; ++i)
        smax[wc * 256 + wr * 64 + mf * 16 + lq * 4 + i] = rowm[mf][i];
  }
  __syncthreads();
  float m2[4][4], rs[4][4];
  #pragma unroll
  for (int mf = 0; mf < 4; ++mf)
    #pragma unroll
    for (int i = 0; i < 4; ++i) {
      int w = wr * 64 + mf * 16 + lq * 4 + i;
      m2[mf][i] = fmaxf(smax[w], smax[256 + w]);
      rs[mf][i] = 0.f;
    }
  #pragma unroll
  for (int mf = 0; mf < 4; ++mf)
    #pragma unroll
    for (int nf = 0; nf < 8; ++nf)
      #pragma unroll
      for (int i = 0; i < 4; ++i) {
        float e = __expf(acc[mf][nf][i] - m2[mf][i]);
        acc[mf][nf][i] = e;
        rs[mf][i] += e;
      }
  #pragma unroll
  for (int mf = 0; mf < 4; ++mf)
    #pragma unroll
    for (int i = 0; i < 4; ++i) {
      float s = rs[mf][i];
      #pragma unroll
      for (int d = 1; d < 16; d <<= 1) s += __shfl_xor(s, d);
      rs[mf][i] = s;
    }
  if (lr == 0) {
    #pragma unroll
    for (int mf = 0; mf < 4; ++mf)
      #pragma unroll
      for (int i = 0; i < 4; ++i)
        ssum[wc * 256 + wr * 64 + mf * 16 + lq * 4 + i] = rs[mf][i];
  }
  __syncthreads();
  // P = e/sum -> bf16 -> PT[v][w]  (overwrites Ft/Gt region; ordered by barriers)
  #pragma unroll
  for (int mf = 0; mf < 4; ++mf)
    #pragma unroll
    for (int i = 0; i < 4; ++i) {
      int w = wr * 64 + mf * 16 + lq * 4 + i;
      float rinv = 1.f / (ssum[w] + ssum[256 + w]);
      #pragma unroll
      for (int nf = 0; nf < 8; ++nf) {
        int v_ = wc * 128 + nf * 16 + lr;
        *(bf16_t*)(smem + ((v_ * 512 + w * 2) ^ swz(v_))) = (bf16_t)(acc[mf][nf][i] * rinv);
      }
    }

  // ---- prefetch H chunks 0..2 (wave owns h rows [wv*32, wv*32+32)) ----
  const bf16_t* hp = mH + plane;
  bf16x8 aP[3][2];
  #pragma unroll
  for (int p = 0; p < 3; ++p)
    #pragma unroll
    for (int mf = 0; mf < 2; ++mf) {
      int h = wv * 32 + mf * 16 + lr;
      aP[p][mf] = *(const bf16x8*)(hp + (size_t)p * 8192 + h * 32 + lq * 8);
    }

  LGKM0(); BAR();   // PT visible; H prefetch stays in flight (vmcnt alive)

  // ---- out = H*P: 8 w-chunks x 16 v-frags, H read once, ZERO barriers ----
  f32x4 oac[2][16];
  #pragma unroll
  for (int mf = 0; mf < 2; ++mf)
    #pragma unroll
    for (int nf = 0; nf < 16; ++nf)
      oac[mf][nf] = fz;

  __builtin_amdgcn_s_setprio(1);
  #pragma unroll
  for (int kc = 0; kc < 8; ++kc) {
    bf16x8 a0 = aP[kc % 3][0], a1 = aP[kc % 3][1];
    if (kc < 5) {
      #pragma unroll
      for (int mf = 0; mf < 2; ++mf) {
        int h = wv * 32 + mf * 16 + lr;
        aP[kc % 3][mf] = *(const bf16x8*)(hp + (size_t)(kc + 3) * 8192 + h * 32 + lq * 8);
      }
    }
    #pragma unroll
    for (int nf = 0; nf < 16; ++nf) {
      int v_ = nf * 16 + lr;
      bf16x8 bq = *(const bf16x8*)(smem + ((v_ * 512 + kc * 64 + lq * 16) ^ swz(v_)));
      oac[0][nf] = __builtin_amdgcn_mfma_f32_16x16x32_bf16(a0, bq, oac[0][nf], 0, 0, 0);
      oac[1][nf] = __builtin_amdgcn_mfma_f32_16x16x32_bf16(a1, bq, oac[1][nf], 0, 0, 0);
    }
  }
  __builtin_amdgcn_s_setprio(0);

  // ---- residual + store f32 (wave writes its 32 rows fully) ----
  #pragma unroll
  for (int mf = 0; mf < 2; ++mf)
    #pragma unroll
    for (int i = 0; i < 4; ++i) {
      int h = wv * 32 + mf * 16 + lq * 4 + i;
      #pragma unroll
      for (int nf = 0; nf < 16; ++nf) {
        int v_ = nf * 16 + lr;
        size_t off = gplane + (size_t)h * 256 + v_;
        out[off] = oac[mf][nf][i] + x[off];
      }
    }
}

// =====================================================================
extern "C" void kernel_launch(void* const* d_in, const int* in_sizes, int n_in,
                              void* d_out, int out_size, void* d_ws, size_t ws_size,
                              hipStream_t stream)
{
  (void)in_sizes; (void)n_in; (void)out_size;
  const float* x   = (const float*)d_in[0];
  const float* Wf  = (const float*)d_in[1];
  const float* bfp = (const float*)d_in[2];
  const float* afp = (const float*)d_in[3];
  const float* Wg  = (const float*)d_in[4];
  const float* bgp = (const float*)d_in[5];
  const float* agp = (const float*)d_in[6];
  const float* Wh  = (const float*)d_in[7];
  const float* bhp = (const float*)d_in[8];
  const float* ahp = (const float*)d_in[9];
  float* out = (float*)d_out;

  const size_t per_map_b = (size_t)C_ * HW_ * sizeof(bf16_t);  // 16 MiB per map per batch
  int nb = 1;
  if      (ws_size >= 3 * 8 * per_map_b + 98304 * 2) nb = 8;
  else if (ws_size >= 3 * 4 * per_map_b + 98304 * 2) nb = 4;
  else if (ws_size >= 3 * 2 * per_map_b + 98304 * 2) nb = 2;

  hipFuncSetAttribute(reinterpret_cast<const void*>(attn_kernel),
                      hipFuncAttributeMaxDynamicSharedMemorySize, SMEM_BYTES);

  bf16_t* mF = (bf16_t*)d_ws;
  bf16_t* mG = mF + (size_t)nb * C_ * HW_;
  bf16_t* mH = mG + (size_t)nb * C_ * HW_;
  bf16_t* Wb = mH + (size_t)nb * C_ * HW_;     // 3 x 32KB swizzled images

  wprep_kernel<<<dim3(64), 256, 0, stream>>>(Wf, Wg, Wh, Wb);

  for (int b0 = 0; b0 < 8; b0 += nb) {
    conv_kernel<<<dim3(512, nb), 256, 0, stream>>>(x, Wb, bfp, afp, bgp, agp,
                                                   bhp, ahp, mF, mG, mH, b0);
    attn_kernel<<<dim3(C_, nb), 512, SMEM_BYTES, stream>>>(mF, mG, mH, x, out, b0);
  }
}

// Round 17
// 389.387 us; speedup vs baseline: 1.0134x; 1.0134x over previous
//
#include <hip/hip_runtime.h>

typedef __bf16 bf16_t;
typedef __bf16 bf16x8 __attribute__((ext_vector_type(8)));
typedef __bf16 bf16x4 __attribute__((ext_vector_type(4)));
typedef float  f32x4  __attribute__((ext_vector_type(4)));

#define HW_ 65536
#define C_  128

// XOR swizzle: spread 16B slots (byte bits [6:4]) by row index. Applied
// identically on LDS write and read; bijective within each 128B span.
__device__ __forceinline__ int swz(int r) { return ((r ^ (r >> 3)) & 7) << 4; }

#define LGKM0()  asm volatile("s_waitcnt lgkmcnt(0)" ::: "memory")
#define VMCNT0() asm volatile("s_waitcnt vmcnt(0)" ::: "memory")
__device__ __forceinline__ void BAR() {
  asm volatile("" ::: "memory");
  __builtin_amdgcn_s_barrier();
  asm volatile("" ::: "memory");
}

typedef __attribute__((address_space(1))) const unsigned int g_u32;
typedef __attribute__((address_space(3))) unsigned int l_u32;

// =====================================================================
// Prep: W f32 -> bf16, written as the EXACT 32KB swizzled LDS image each
// conv tile wants: img_byte[(o*256 + c*2) ^ swz(o)] = bf16(W[o][c]).
// conv then stages it with linear global_load_lds (zero VALU, async).
// =====================================================================
__global__ void wprep_kernel(const float* __restrict__ Wf, const float* __restrict__ Wg,
                             const float* __restrict__ Wh, bf16_t* __restrict__ dst)
{
  int i = blockIdx.x * 256 + threadIdx.x;          // 0..16383
  int o = i >> 7, c = i & 127;
  int boff = (o * 256 + c * 2) ^ swz(o);
  char* d = (char*)dst;
  *(bf16_t*)(d + boff)         = (bf16_t)Wf[i];
  *(bf16_t*)(d + 32768 + boff) = (bf16_t)Wg[i];
  *(bf16_t*)(d + 65536 + boff) = (bf16_t)Wh[i];
}

// =====================================================================
// Phase 1 (R15 form, measured ~150us): map = PReLU(W*x + b).
// Per-b GEMM M=128,K=128,N=128/WG.  LDS: Xs [0,32K) transposed bf16 x;
// Ws [32K,64K) = current W image (staged async via global_load_lds).
// Staging for conv k+1 issued after conv k's post-MFMA barrier, streaming
// under conv k's epilogue stores.
// HBLK: mH w-blocked [c][w>>6][h][w&63] for attn PV staging reads.
// =====================================================================
__device__ __forceinline__ void stage_w(char* lds, const bf16_t* __restrict__ Wimg,
                                        int wv, int t)
{
  #pragma unroll
  for (int rep = 0; rep < 8; ++rep) {
    const char* src = (const char*)Wimg + (rep * 256 + t) * 16;
    char* dst = lds + 32768 + (rep * 4 + wv) * 1024;      // wave-uniform base
    __builtin_amdgcn_global_load_lds((g_u32*)src, (l_u32*)dst, 16, 0, 0);
  }
}

__device__ __forceinline__ void conv_mfma(const char* lds, f32x4 (&acc)[2][8],
                                          int wv, int lr, int lq)
{
  const f32x4 fz = {0.f, 0.f, 0.f, 0.f};
  #pragma unroll
  for (int mf = 0; mf < 2; ++mf)
    #pragma unroll
    for (int nf = 0; nf < 8; ++nf)
      acc[mf][nf] = fz;

  #pragma unroll
  for (int ks = 0; ks < 4; ++ks) {
    int kb = ks * 32 + lq * 8;
    bf16x8 a[2], bb[8];
    #pragma unroll
    for (int mf = 0; mf < 2; ++mf) {
      int m = wv * 32 + mf * 16 + lr;
      a[mf] = *(const bf16x8*)(lds + 32768 + ((m * 256 + kb * 2) ^ swz(m)));
    }
    #pragma unroll
    for (int nf = 0; nf < 8; ++nf) {
      int n = nf * 16 + lr;
      bb[nf] = *(const bf16x8*)(lds + ((n * 256 + kb * 2) ^ swz(n)));
    }
    #pragma unroll
    for (int mf = 0; mf < 2; ++mf)
      #pragma unroll
      for (int nf = 0; nf < 8; ++nf)
        acc[mf][nf] = __builtin_amdgcn_mfma_f32_16x16x32_bf16(a[mf], bb[nf], acc[mf][nf], 0, 0, 0);
  }
}

template<bool HBLK>
__device__ __forceinline__ void conv_epi(const f32x4 (&acc)[2][8],
                                         const float* __restrict__ bias, float alpha,
                                         bf16_t* __restrict__ dst, size_t pb,
                                         int wv, int lr, int lq, int s0)
{
  #pragma unroll
  for (int mf = 0; mf < 2; ++mf) {
    #pragma unroll
    for (int i = 0; i < 4; ++i) {
      int o = wv * 32 + mf * 16 + lq * 4 + i;
      float bo = bias[o];
      #pragma unroll
      for (int nf = 0; nf < 8; ++nf) {
        int s = s0 + nf * 16 + lr;
        float v = acc[mf][nf][i] + bo;
        v = (v >= 0.f) ? v : alpha * v;
        size_t off;
        if (HBLK) {                       // w-blocked layout [c][w>>6][h][w&63]
          int h = s >> 8, w = s & 255;
          off = pb + (size_t)o * HW_ + (size_t)(w >> 6) * 16384 + h * 64 + (w & 63);
        } else {
          off = pb + (size_t)o * HW_ + s; // natural [c][h][w]
        }
        dst[off] = (bf16_t)v;
      }
    }
  }
}

__global__ __launch_bounds__(256, 2) void conv_kernel(
    const float* __restrict__ x, const bf16_t* __restrict__ Wimg,
    const float* __restrict__ bfp, const float* __restrict__ afp,
    const float* __restrict__ bgp, const float* __restrict__ agp,
    const float* __restrict__ bhp, const float* __restrict__ ahp,
    bf16_t* __restrict__ mF, bf16_t* __restrict__ mG, bf16_t* __restrict__ mH, int b0)
{
  __shared__ __align__(16) char lds[65536];
  const int t = threadIdx.x;
  const int bloc = blockIdx.y;
  const int s0 = blockIdx.x * 128;
  const size_t xbase = ((size_t)(b0 + bloc) * C_) * HW_ + s0;
  const int wv = t >> 6, lane = t & 63, lr = lane & 15, lq = lane >> 4;
  const size_t pb = (size_t)bloc * C_ * HW_;

  // issue W_f staging async; stage x tile meanwhile
  stage_w(lds, Wimg, wv, t);

  #pragma unroll
  for (int rep = 0; rep < 4; ++rep) {
    int q = rep * 256 + t;
    int c0 = (q >> 5) * 4, sl0 = (q & 31) * 4;
    f32x4 r[4];
    #pragma unroll
    for (int i = 0; i < 4; ++i)
      r[i] = *(const f32x4*)(x + xbase + (size_t)(c0 + i) * HW_ + sl0);
    #pragma unroll
    for (int js = 0; js < 4; ++js) {
      int s = sl0 + js;
      bf16x4 v;
      v[0] = (bf16_t)r[0][js]; v[1] = (bf16_t)r[1][js];
      v[2] = (bf16_t)r[2][js]; v[3] = (bf16_t)r[3][js];
      *(bf16x4*)(lds + ((s * 256 + c0 * 2) ^ swz(s))) = v;
    }
  }
  __syncthreads();                       // Xs lgkm + W_f vmcnt drained

  f32x4 acc[2][8];

  // ---- conv f ----
  conv_mfma(lds, acc, wv, lr, lq);
  BAR();                                 // all Ws(f) reads done
  stage_w(lds, Wimg + 16384, wv, t);     // W_g streams under f's epilogue
  conv_epi<false>(acc, bfp, afp[0], mF, pb, wv, lr, lq, s0);
  VMCNT0(); BAR();                       // W_g landed everywhere

  // ---- conv g ----
  conv_mfma(lds, acc, wv, lr, lq);
  BAR();
  stage_w(lds, Wimg + 32768, wv, t);     // W_h streams under g's epilogue
  conv_epi<false>(acc, bgp, agp[0], mG, pb, wv, lr, lq, s0);
  VMCNT0(); BAR();

  // ---- conv h ----
  conv_mfma(lds, acc, wv, lr, lq);
  conv_epi<true>(acc, bhp, ahp[0], mH, pb, wv, lr, lq, s0);
}

// =====================================================================
// Phase 2 (R10 form — best verified: attn 235.6us): 512 thr / 8 waves.
// LDS map (155648 B):
//   [0,32768)        Ft chunk  [w=256][h=64] bf16 swizzled   (S phase)
//   [32768,65536)    Gt chunk  [v=256][h=64] bf16 swizzled   (S phase)
//   [0,131072)       PT        [v=256][w=256] bf16 swizzled  (PV phase)
//   [131072,151552)  Hs chunk  [h=256][w=32] bf16, 80B row pitch
//   [151552,153600)  smax [2][256] f32 ; [153600,155648) ssum [2][256] f32
// S: depth-1 global prefetch kept in flight across raw barriers (T14).
// PV: H chunk k+1 issued after chunk k's LDS write (T14).
// Register file is FULL at 2 waves/SIMD (S-acc 128 AGPR + staging = 256
// unified budget) — do not add state anywhere (R11-R13 spills); LDS at
// 152K pins 1 WG/CU.  R16 proved the PV barriers are already hidden.
// =====================================================================
#define GT_OFF  32768
#define HS_OFF  131072
#define SMAX_OFF 151552
#define SSUM_OFF 153600
#define SMEM_BYTES 155648

__global__ __launch_bounds__(512, 2) void attn_kernel(
    const bf16_t* __restrict__ mF, const bf16_t* __restrict__ mG, const bf16_t* __restrict__ mH,
    const float* __restrict__ x, float* __restrict__ out, int b0)
{
  extern __shared__ __align__(16) char smem[];
  const int t = threadIdx.x;
  const int c = blockIdx.x, bloc = blockIdx.y;
  const int wv = t >> 6, lane = t & 63, lr = lane & 15, lq = lane >> 4;
  const int wr = wv >> 1, wc = wv & 1;
  const size_t plane  = ((size_t)bloc * C_ + c) * HW_;            // maps (per-pass)
  const size_t gplane = (((size_t)(b0 + bloc)) * C_ + c) * HW_;   // x / out (global)

  const f32x4 fz = {0.f, 0.f, 0.f, 0.f};
  f32x4 acc[4][8];
  #pragma unroll
  for (int mf = 0; mf < 4; ++mf)
    #pragma unroll
    for (int nf = 0; nf < 8; ++nf)
      acc[mf][nf] = fz;

  const int hq = t >> 5, wb8 = t & 31;   // staging decomposition

  // ---- S = F^T G, K(=h) chunks of 64; depth-1 prefetch across barriers ----
  bf16x8 pfF[4], pfG[4];
  #pragma unroll
  for (int i = 0; i < 4; ++i) {
    pfF[i] = *(const bf16x8*)(mF + plane + (size_t)(hq * 4 + i) * 256 + wb8 * 8);
    pfG[i] = *(const bf16x8*)(mG + plane + (size_t)(hq * 4 + i) * 256 + wb8 * 8);
  }

  for (int hb = 0; hb < 256; hb += 64) {
    BAR();                             // prev chunk's LDS reads done; Ft/Gt writable
    #pragma unroll
    for (int j = 0; j < 8; ++j) {      // transpose-write (waits vmcnt on pf regs)
      int w = wb8 * 8 + j;
      bf16x4 v; v[0] = pfF[0][j]; v[1] = pfF[1][j]; v[2] = pfF[2][j]; v[3] = pfF[3][j];
      *(bf16x4*)(smem + ((w * 128 + hq * 8) ^ swz(w))) = v;
      bf16x4 g; g[0] = pfG[0][j]; g[1] = pfG[1][j]; g[2] = pfG[2][j]; g[3] = pfG[3][j];
      *(bf16x4*)(smem + GT_OFF + ((w * 128 + hq * 8) ^ swz(w))) = g;
    }
    if (hb < 192) {                    // issue next chunk; flies across BAR + MFMAs
      #pragma unroll
      for (int i = 0; i < 4; ++i) {
        pfF[i] = *(const bf16x8*)(mF + plane + (size_t)(hb + 64 + hq * 4 + i) * 256 + wb8 * 8);
        pfG[i] = *(const bf16x8*)(mG + plane + (size_t)(hb + 64 + hq * 4 + i) * 256 + wb8 * 8);
      }
    }
    LGKM0(); BAR();                    // LDS writes visible; vmcnt NOT drained
    #pragma unroll
    for (int k0 = 0; k0 < 64; k0 += 32) {
      int kb = k0 + lq * 8;
      bf16x8 a[4], bb[8];
      #pragma unroll
      for (int mf = 0; mf < 4; ++mf) {
        int m = wr * 64 + mf * 16 + lr;
        a[mf] = *(const bf16x8*)(smem + ((m * 128 + kb * 2) ^ swz(m)));
      }
      #pragma unroll
      for (int nf = 0; nf < 8; ++nf) {
        int n = wc * 128 + nf * 16 + lr;
        bb[nf] = *(const bf16x8*)(smem + GT_OFF + ((n * 128 + kb * 2) ^ swz(n)));
      }
      #pragma unroll
      for (int mf = 0; mf < 4; ++mf)
        #pragma unroll
        for (int nf = 0; nf < 8; ++nf)
          acc[mf][nf] = __builtin_amdgcn_mfma_f32_16x16x32_bf16(a[mf], bb[nf], acc[mf][nf], 0, 0, 0);
    }
  }

  // ---- softmax over v (rows w) ----
  float* smax = (float*)(smem + SMAX_OFF);
  float* ssum = (float*)(smem + SSUM_OFF);
  float rowm[4][4];
  #pragma unroll
  for (int mf = 0; mf < 4; ++mf)
    #pragma unroll
    for (int i = 0; i < 4; ++i) {
      float m = acc[mf][0][i];
      #pragma unroll
      for (int nf = 1; nf < 8; ++nf) m = fmaxf(m, acc[mf][nf][i]);
      #pragma unroll
      for (int d = 1; d < 16; d <<= 1) m = fmaxf(m, __shfl_xor(m, d));
      rowm[mf][i] = m;
    }
  if (lr == 0) {
    #pragma unroll
    for (int mf = 0; mf < 4; ++mf)
      #pragma unroll
      for (int i = 0; i < 4; ++i)
        smax[wc * 256 + wr * 64 + mf * 16 + lq * 4 + i] = rowm[mf][i];
  }
  __syncthreads();
  float m2[4][4], rs[4][4];
  #pragma unroll
  for (int mf = 0; mf < 4; ++mf)
    #pragma unroll
    for (int i = 0; i < 4; ++i) {
      int w = wr * 64 + mf * 16 + lq * 4 + i;
      m2[mf][i] = fmaxf(smax[w], smax[256 + w]);
      rs[mf][i] = 0.f;
    }
  #pragma unroll
  for (int mf = 0; mf < 4; ++mf)
    #pragma unroll
    for (int nf = 0; nf < 8; ++nf)
      #pragma unroll
      for (int i = 0; i < 4; ++i) {
        float e = __expf(acc[mf][nf][i] - m2[mf][i]);
        acc[mf][nf][i] = e;
        rs[mf][i] += e;
      }
  #pragma unroll
  for (int mf = 0; mf < 4; ++mf)
    #pragma unroll
    for (int i = 0; i < 4; ++i) {
      float s = rs[mf][i];
      #pragma unroll
      for (int d = 1; d < 16; d <<= 1) s += __shfl_xor(s, d);
      rs[mf][i] = s;
    }
  if (lr == 0) {
    #pragma unroll
    for (int mf = 0; mf < 4; ++mf)
      #pragma unroll
      for (int i = 0; i < 4; ++i)
        ssum[wc * 256 + wr * 64 + mf * 16 + lq * 4 + i] = rs[mf][i];
  }
  __syncthreads();
  // P = e/sum -> bf16 -> PT[v][w]  (overwrites Ft/Gt region; ordered by barriers)
  #pragma unroll
  for (int mf = 0; mf < 4; ++mf)
    #pragma unroll
    for (int i = 0; i < 4; ++i) {
      int w = wr * 64 + mf * 16 + lq * 4 + i;
      float rinv = 1.f / (ssum[w] + ssum[256 + w]);
      #pragma unroll
      for (int nf = 0; nf < 8; ++nf) {
        int v_ = wc * 128 + nf * 16 + lr;
        *(bf16_t*)(smem + ((v_ * 512 + w * 2) ^ swz(v_))) = (bf16_t)(acc[mf][nf][i] * rinv);
      }
    }

  // ---- out = H*P, K(=w) chunks of 32; H loads issued one chunk ahead ----
  #pragma unroll
  for (int mf = 0; mf < 4; ++mf)
    #pragma unroll
    for (int nf = 0; nf < 8; ++nf)
      acc[mf][nf] = fz;

  // issue chunk-0 H loads early: latency hides under P-write + first barrier
  bf16x8 hreg[2];
  {
    #pragma unroll
    for (int rep = 0; rep < 2; ++rep) {
      int u = rep * 512 + t;
      int h = u >> 2, wl0 = (u & 3) * 8;
      hreg[rep] = *(const bf16x8*)(mH + plane + h * 64 + wl0);
    }
  }

  for (int wk = 0; wk < 8; ++wk) {
    LGKM0(); BAR();                    // P-write / prev MFMA reads done; Hs writable
    {
      #pragma unroll
      for (int rep = 0; rep < 2; ++rep) {
        int u = rep * 512 + t;
        int h = u >> 2, wl0 = (u & 3) * 8;
        *(bf16x8*)(smem + HS_OFF + h * 80 + wl0 * 2) = hreg[rep];  // waits vmcnt on hreg
      }
    }
    if (wk < 7) {                      // issue next chunk; stays in flight across BAR
      const size_t hbase = plane + (size_t)((wk + 1) >> 1) * 16384 + (size_t)((wk + 1) & 1) * 32;
      #pragma unroll
      for (int rep = 0; rep < 2; ++rep) {
        int u = rep * 512 + t;
        int h = u >> 2, wl0 = (u & 3) * 8;
        hreg[rep] = *(const bf16x8*)(mH + hbase + h * 64 + wl0);
      }
    }
    LGKM0(); BAR();                    // Hs writes visible; vmcnt NOT drained
    int kb = lq * 8;
    bf16x8 a[4], bb[8];
    #pragma unroll
    for (int mf = 0; mf < 4; ++mf) {
      int m = wr * 64 + mf * 16 + lr;
      a[mf] = *(const bf16x8*)(smem + HS_OFF + m * 80 + kb * 2);
    }
    #pragma unroll
    for (int nf = 0; nf < 8; ++nf) {
      int n = wc * 128 + nf * 16 + lr;
      int kg = wk * 32 + kb;
      bb[nf] = *(const bf16x8*)(smem + ((n * 512 + kg * 2) ^ swz(n)));
    }
    #pragma unroll
    for (int mf = 0; mf < 4; ++mf)
      #pragma unroll
      for (int nf = 0; nf < 8; ++nf)
        acc[mf][nf] = __builtin_amdgcn_mfma_f32_16x16x32_bf16(a[mf], bb[nf], acc[mf][nf], 0, 0, 0);
  }

  // ---- residual + store f32 ----
  #pragma unroll
  for (int mf = 0; mf < 4; ++mf)
    #pragma unroll
    for (int i = 0; i < 4; ++i) {
      int h = wr * 64 + mf * 16 + lq * 4 + i;
      #pragma unroll
      for (int nf = 0; nf < 8; ++nf) {
        int v_ = wc * 128 + nf * 16 + lr;
        size_t off = gplane + (size_t)h * 256 + v_;
        out[off] = acc[mf][nf][i] + x[off];
      }
    }
}

// =====================================================================
extern "C" void kernel_launch(void* const* d_in, const int* in_sizes, int n_in,
                              void* d_out, int out_size, void* d_ws, size_t ws_size,
                              hipStream_t stream)
{
  (void)in_sizes; (void)n_in; (void)out_size;
  const float* x   = (const float*)d_in[0];
  const float* Wf  = (const float*)d_in[1];
  const float* bfp = (const float*)d_in[2];
  const float* afp = (const float*)d_in[3];
  const float* Wg  = (const float*)d_in[4];
  const float* bgp = (const float*)d_in[5];
  const float* agp = (const float*)d_in[6];
  const float* Wh  = (const float*)d_in[7];
  const float* bhp = (const float*)d_in[8];
  const float* ahp = (const float*)d_in[9];
  float* out = (float*)d_out;

  const size_t per_map_b = (size_t)C_ * HW_ * sizeof(bf16_t);  // 16 MiB per map per batch
  int nb = 1;
  if      (ws_size >= 3 * 8 * per_map_b + 98304 * 2) nb = 8;
  else if (ws_size >= 3 * 4 * per_map_b + 98304 * 2) nb = 4;
  else if (ws_size >= 3 * 2 * per_map_b + 98304 * 2) nb = 2;

  hipFuncSetAttribute(reinterpret_cast<const void*>(attn_kernel),
                      hipFuncAttributeMaxDynamicSharedMemorySize, SMEM_BYTES);

  bf16_t* mF = (bf16_t*)d_ws;
  bf16_t* mG = mF + (size_t)nb * C_ * HW_;
  bf16_t* mH = mG + (size_t)nb * C_ * HW_;
  bf16_t* Wb = mH + (size_t)nb * C_ * HW_;     // 3 x 32KB swizzled images

  wprep_kernel<<<dim3(64), 256, 0, stream>>>(Wf, Wg, Wh, Wb);

  for (int b0 = 0; b0 < 8; b0 += nb) {
    conv_kernel<<<dim3(512, nb), 256, 0, stream>>>(x, Wb, bfp, afp, bgp, agp,
                                                   bhp, ahp, mF, mG, mH, b0);
    attn_kernel<<<dim3(C_, nb), 512, SMEM_BYTES, stream>>>(mF, mG, mH, x, out, b0);
  }
}